// Round 1
// baseline (97.087 us; speedup 1.0000x reference)
//
#include <hip/hip_runtime.h>
#include <hip/hip_bf16.h>
#include <stdint.h>

// DotReluAttention: out = relu(Q K^T / 64) V   (B=2,H=8,S=4096,D=64, fp32 io)
// Pre-pass: fp32->bf16 into ws (Q/64 row-major; K 64x64 swizzled tiles; V transposed+swizzled tiles).
// Main: 32x32x16 bf16 MFMA, swapped QK^T, in-register P, 2-way K-split per block.

#define NH 16
#define SEQ 4096
#define DD 64
#define HE (SEQ*DD)            // 262144 elems / head
#define HB (HE*2)              // 524288 bytes / head (bf16)
#define Q16_OFF 0
#define K16_OFF (NH*HB)        // 8388608
#define V16_OFF (2*NH*HB)      // 16777216
#define WS_NEED (3*NH*HB)      // 25165824

typedef __attribute__((ext_vector_type(8)))  short    bf16x8;
typedef __attribute__((ext_vector_type(16))) float    f32x16;
typedef __attribute__((ext_vector_type(4)))  uint32_t u32x4;

__device__ inline uint32_t f2bf1(float f) {
  return (uint32_t)__builtin_bit_cast(unsigned short, __float2bfloat16(f));
}
__device__ inline uint32_t pack2bf(float a, float b) {
  return f2bf1(a) | (f2bf1(b) << 16);
}

__global__ __launch_bounds__(256) void prepass_kernel(const float* __restrict__ Q,
                                                      const float* __restrict__ K,
                                                      const float* __restrict__ V,
                                                      char* __restrict__ ws) {
  __shared__ float vt[64*65];
  int bx = blockIdx.x, tid = threadIdx.x;
  if (bx < 2048) {                       // Q: convert + scale 1/64, row-major
    size_t base = ((size_t)bx*256 + tid)*8;
    const float4* s = (const float4*)(Q + base);
    float4 a = s[0], b = s[1];
    const float sc = 1.0f/64.0f;
    u32x4 o;
    o.x = pack2bf(a.x*sc, a.y*sc);
    o.y = pack2bf(a.z*sc, a.w*sc);
    o.z = pack2bf(b.x*sc, b.y*sc);
    o.w = pack2bf(b.z*sc, b.w*sc);
    *(u32x4*)(ws + Q16_OFF + base*2) = o;
  } else if (bx < 3072) {                // K: 64x64 tiles, row-major, XOR-swizzled
    int tile = bx - 2048;
    int head = tile >> 6, t = tile & 63;
    int r = tid >> 2, c0 = (tid & 3) * 16;
    const float4* s4 = (const float4*)(K + (size_t)head*HE + ((size_t)(t*64 + r))*64 + c0);
    float4 f0 = s4[0], f1 = s4[1], f2 = s4[2], f3 = s4[3];
    u32x4 c_lo, c_hi;
    c_lo.x = pack2bf(f0.x, f0.y); c_lo.y = pack2bf(f0.z, f0.w);
    c_lo.z = pack2bf(f1.x, f1.y); c_lo.w = pack2bf(f1.z, f1.w);
    c_hi.x = pack2bf(f2.x, f2.y); c_hi.y = pack2bf(f2.z, f2.w);
    c_hi.z = pack2bf(f3.x, f3.y); c_hi.w = pack2bf(f3.z, f3.w);
    char* tb = ws + K16_OFF + ((size_t)head*64 + t)*8192;
    int sw = (r & 7) << 4;
    *(u32x4*)(tb + r*128 + ((c0*2)      ^ sw)) = c_lo;
    *(u32x4*)(tb + r*128 + ((c0*2 + 16) ^ sw)) = c_hi;
  } else {                               // V: transpose via LDS, then swizzled tiles [d][k]
    int tile = bx - 3072;
    int head = tile >> 6, t = tile & 63;
    int k = tid >> 2, c0 = (tid & 3)*16;
    const float4* s4 = (const float4*)(V + (size_t)head*HE + ((size_t)(t*64 + k))*64 + c0);
    float4 f0 = s4[0], f1 = s4[1], f2 = s4[2], f3 = s4[3];
    float tmp[16] = {f0.x,f0.y,f0.z,f0.w, f1.x,f1.y,f1.z,f1.w,
                     f2.x,f2.y,f2.z,f2.w, f3.x,f3.y,f3.z,f3.w};
    #pragma unroll
    for (int j = 0; j < 16; ++j) vt[k*65 + c0 + j] = tmp[j];
    __syncthreads();
    int d = tid >> 2, k0 = (tid & 3)*16;
    float v2[16];
    #pragma unroll
    for (int j = 0; j < 16; ++j) v2[j] = vt[(k0 + j)*65 + d];
    u32x4 c_lo, c_hi;
    c_lo.x = pack2bf(v2[0],  v2[1]);  c_lo.y = pack2bf(v2[2],  v2[3]);
    c_lo.z = pack2bf(v2[4],  v2[5]);  c_lo.w = pack2bf(v2[6],  v2[7]);
    c_hi.x = pack2bf(v2[8],  v2[9]);  c_hi.y = pack2bf(v2[10], v2[11]);
    c_hi.z = pack2bf(v2[12], v2[13]); c_hi.w = pack2bf(v2[14], v2[15]);
    char* tb = ws + V16_OFF + ((size_t)head*64 + t)*8192;
    int sw = (d & 7) << 4;
    *(u32x4*)(tb + d*128 + ((k0*2)      ^ sw)) = c_lo;
    *(u32x4*)(tb + d*128 + ((k0*2 + 16) ^ sw)) = c_hi;
  }
}

__global__ __launch_bounds__(256, 2) void attn_kernel(const char* __restrict__ ws,
                                                      float* __restrict__ out) {
  __shared__ __align__(16) char lds[8*8192];   // [group][dbuf][K|V] x 8KB
  int bx = blockIdx.x;
  int head = bx >> 5, qblk = bx & 31;
  int tid = threadIdx.x;
  int lane = tid & 63, w = tid >> 6;
  int l31 = lane & 31, h = lane >> 5;
  int g  = w >> 1;    // k-group: tiles [g*32, g*32+32)
  int mq = w & 1;     // q-half of the 128-row block

  const char* q16 = ws + Q16_OFF + (size_t)head*HB;
  const char* k16 = ws + K16_OFF + (size_t)head*HB;
  const char* v16 = ws + V16_OFF + (size_t)head*HB;
  int qrow0 = qblk*128 + mq*64;

  // Q fragments (B-operand of swapped QK^T): Q[qrow0+m*32+l31][t*16+h*8+e]
  bf16x8 qf[2][4];
  #pragma unroll
  for (int m = 0; m < 2; ++m)
    #pragma unroll
    for (int t = 0; t < 4; ++t)
      qf[m][t] = *(const bf16x8*)(q16 + ((size_t)(qrow0 + m*32 + l31)*64 + t*16 + h*8)*2);

  f32x16 o[2][2];
  #pragma unroll
  for (int m = 0; m < 2; ++m)
    #pragma unroll
    for (int nd = 0; nd < 2; ++nd)
      #pragma unroll
      for (int i = 0; i < 16; ++i) o[m][nd][i] = 0.f;

  char* ldsg = lds + g*4*8192;

  auto stage = [&](int cur, int kt) {
    const char* ktile = k16 + (size_t)(g*32 + kt)*8192;
    const char* vtile = v16 + (size_t)(g*32 + kt)*8192;
    char* lk = ldsg + (cur*2 + 0)*8192;
    char* lv = ldsg + (cur*2 + 1)*8192;
    #pragma unroll
    for (int c = 0; c < 4; ++c) {
      int off = (mq*4 + c)*1024;
      __builtin_amdgcn_global_load_lds(
          (const __attribute__((address_space(1))) void*)(ktile + off + lane*16),
          (__attribute__((address_space(3))) void*)(lk + off), 16, 0, 0);
      __builtin_amdgcn_global_load_lds(
          (const __attribute__((address_space(1))) void*)(vtile + off + lane*16),
          (__attribute__((address_space(3))) void*)(lv + off), 16, 0, 0);
    }
  };

  auto compute = [&](int cur) {
    const char* lk = ldsg + (cur*2 + 0)*8192;
    const char* lv = ldsg + (cur*2 + 1)*8192;
    // swapped QK^T: st[m][n] = S^T tile (rows k = n*32.., cols q = m*32..)
    f32x16 st[2][2];
    #pragma unroll
    for (int n = 0; n < 2; ++n) {
      bf16x8 kf[4];
      int row = n*32 + l31;
      int sw = (row & 7) << 4;
      #pragma unroll
      for (int t = 0; t < 4; ++t)
        kf[t] = *(const bf16x8*)(lk + row*128 + ((t*32 + h*16) ^ sw));
      #pragma unroll
      for (int m = 0; m < 2; ++m) {
        f32x16 acc;
        #pragma unroll
        for (int i = 0; i < 16; ++i) acc[i] = 0.f;
        #pragma unroll
        for (int t = 0; t < 4; ++t)
          acc = __builtin_amdgcn_mfma_f32_32x32x16_bf16(kf[t], qf[m][t], acc, 0, 0, 0);
        st[m][n] = acc;
      }
    }
    // relu + pack + half-wave exchange -> PV A-fragments (in registers)
    bf16x8 pa[2][4];
    #pragma unroll
    for (int m = 0; m < 2; ++m)
      #pragma unroll
      for (int n = 0; n < 2; ++n) {
        float p[16];
        #pragma unroll
        for (int r = 0; r < 16; ++r) p[r] = fmaxf(st[m][n][r], 0.f);
        #pragma unroll
        for (int kn = 0; kn < 2; ++kn) {
          uint32_t wloA = pack2bf(p[kn*8+0], p[kn*8+1]);
          uint32_t wloB = pack2bf(p[kn*8+2], p[kn*8+3]);
          uint32_t whiA = pack2bf(p[kn*8+4], p[kn*8+5]);
          uint32_t whiB = pack2bf(p[kn*8+6], p[kn*8+7]);
          uint32_t sendA = h ? wloA : whiA;
          uint32_t sendB = h ? wloB : whiB;
          uint32_t yA = (uint32_t)__shfl_xor((int)sendA, 32, 64);
          uint32_t yB = (uint32_t)__shfl_xor((int)sendB, 32, 64);
          union { uint32_t u[4]; bf16x8 v; } pk;
          pk.u[0] = h ? yA   : wloA;
          pk.u[1] = h ? yB   : wloB;
          pk.u[2] = h ? whiA : yA;
          pk.u[3] = h ? whiB : yB;
          pa[m][n*2 + kn] = pk.v;
        }
      }
    // V fragments (B-operand): V[ks*16+h*8+e][nd*32+l31] from transposed tile
    bf16x8 vf[2][4];
    #pragma unroll
    for (int nd = 0; nd < 2; ++nd) {
      int row = nd*32 + l31;
      int sw = (row & 7) << 4;
      #pragma unroll
      for (int ks = 0; ks < 4; ++ks)
        vf[nd][ks] = *(const bf16x8*)(lv + row*128 + ((ks*32 + h*16) ^ sw));
    }
    #pragma unroll
    for (int m = 0; m < 2; ++m)
      #pragma unroll
      for (int nd = 0; nd < 2; ++nd)
        #pragma unroll
        for (int ks = 0; ks < 4; ++ks)
          o[m][nd] = __builtin_amdgcn_mfma_f32_32x32x16_bf16(pa[m][ks], vf[nd][ks], o[m][nd], 0, 0, 0);
  };

  stage(0, 0);
  __syncthreads();
  #pragma unroll 1
  for (int kt = 0; kt < 32; ++kt) {
    int cur = kt & 1;
    if (kt + 1 < 32) stage(cur ^ 1, kt + 1);
    compute(cur);
    __syncthreads();
  }

  // cross-k-group O reduction: g1 -> LDS, g0 adds and stores
  float* red = (float*)lds;
  if (g == 1) {
    #pragma unroll
    for (int m = 0; m < 2; ++m)
      #pragma unroll
      for (int nd = 0; nd < 2; ++nd)
        #pragma unroll
        for (int r = 0; r < 16; ++r) {
          int ql = m*32 + (r & 3) + 8*(r >> 2) + 4*h;
          red[mq*4096 + ql*64 + nd*32 + l31] = o[m][nd][r];
        }
  }
  __syncthreads();
  if (g == 0) {
    float* outh = out + (size_t)head*HE;
    #pragma unroll
    for (int m = 0; m < 2; ++m)
      #pragma unroll
      for (int nd = 0; nd < 2; ++nd)
        #pragma unroll
        for (int r = 0; r < 16; ++r) {
          int ql = m*32 + (r & 3) + 8*(r >> 2) + 4*h;
          float v = o[m][nd][r] + red[mq*4096 + ql*64 + nd*32 + l31];
          outh[(size_t)(qrow0 + ql)*64 + nd*32 + l31] = v;
        }
  }
}

extern "C" void kernel_launch(void* const* d_in, const int* in_sizes, int n_in,
                              void* d_out, int out_size, void* d_ws, size_t ws_size,
                              hipStream_t stream) {
  if (n_in < 3 || ws_size < (size_t)WS_NEED) return;  // ws too small -> fail visibly
  const float* Q = (const float*)d_in[0];
  const float* K = (const float*)d_in[1];
  const float* V = (const float*)d_in[2];
  float* out = (float*)d_out;
  char* ws = (char*)d_ws;
  hipLaunchKernelGGL(prepass_kernel, dim3(4096), dim3(256), 0, stream, Q, K, V, ws);
  hipLaunchKernelGGL(attn_kernel,    dim3(512),  dim3(256), 0, stream, ws, out);
}

// Round 3
// 87.809 us; speedup vs baseline: 1.1057x; 1.1057x over previous
//
#include <hip/hip_runtime.h>
#include <hip/hip_bf16.h>
#include <stdint.h>

// DotReluAttention: out = relu(Q K^T / 64) V   (B=2,H=8,S=4096,D=64, fp32 io)
// Pre-pass: fp32->bf16 into ws (Q/64 row-major; K 64x64 swizzled tiles; V transposed+swizzled tiles).
// Main: 32x32x16 bf16 MFMA, swapped QK^T, in-register P via permlane32_swap,
//       packed-f16 relu on bf16 bit patterns (inline asm), hoisted zero accumulator,
//       setprio around MFMA clusters, 2-way K-split per block.

#define NH 16
#define SEQ 4096
#define DD 64
#define HE (SEQ*DD)            // 262144 elems / head
#define HB (HE*2)              // 524288 bytes / head (bf16)
#define Q16_OFF 0
#define K16_OFF (NH*HB)        // 8388608
#define V16_OFF (2*NH*HB)      // 16777216
#define WS_NEED (3*NH*HB)      // 25165824

typedef __attribute__((ext_vector_type(8)))  short    bf16x8;
typedef __attribute__((ext_vector_type(16))) float    f32x16;
typedef __attribute__((ext_vector_type(4)))  uint32_t u32x4;

__device__ inline uint32_t f2bf1(float f) {
  return (uint32_t)__builtin_bit_cast(unsigned short, __float2bfloat16(f));
}
__device__ inline uint32_t pack2bf(float a, float b) {
  return f2bf1(a) | (f2bf1(b) << 16);
}
// relu on a packed pair of bf16 via v_pk_max_f16: finite bf16 bit-patterns
// (|x| well below f16-NaN territory when viewed as f16? they're just 16-bit
// patterns; positive IEEE patterns are order-isomorphic and sign bit is bit15
// in both formats) -> max(x, +0) zeroes exactly the negative halves.
// Our |S| <= ~64 in bf16 => exponent field < 0x1F as f16 only for small
// patterns; bf16 0x7F80+ (inf/nan) never occurs for |S|<3e38. Patterns with
// f16-exponent 0x1F (bf16 |x| >= 2^16... actually bf16 pattern bits 14:10 all
// ones occurs for bf16 values with exponent bits 0b11111 in that window, i.e.
// |x| in [2^97, 2^129)) cannot arise here (|S|<=64*sqrt? bounded by ~2^13).
__device__ inline uint32_t relu2(uint32_t w) {
  uint32_t r;
  asm("v_pk_max_f16 %0, %1, 0" : "=v"(r) : "v"(w));
  return r;
}

__global__ __launch_bounds__(256) void prepass_kernel(const float* __restrict__ Q,
                                                      const float* __restrict__ K,
                                                      const float* __restrict__ V,
                                                      char* __restrict__ ws) {
  __shared__ float vt[64*65];
  int bx = blockIdx.x, tid = threadIdx.x;
  if (bx < 2048) {                       // Q: convert + scale 1/64, row-major
    size_t base = ((size_t)bx*256 + tid)*8;
    const float4* s = (const float4*)(Q + base);
    float4 a = s[0], b = s[1];
    const float sc = 1.0f/64.0f;
    u32x4 o;
    o.x = pack2bf(a.x*sc, a.y*sc);
    o.y = pack2bf(a.z*sc, a.w*sc);
    o.z = pack2bf(b.x*sc, b.y*sc);
    o.w = pack2bf(b.z*sc, b.w*sc);
    *(u32x4*)(ws + Q16_OFF + base*2) = o;
  } else if (bx < 3072) {                // K: 64x64 tiles, row-major, XOR-swizzled
    int tile = bx - 2048;
    int head = tile >> 6, t = tile & 63;
    int r = tid >> 2, c0 = (tid & 3) * 16;
    const float4* s4 = (const float4*)(K + (size_t)head*HE + ((size_t)(t*64 + r))*64 + c0);
    float4 f0 = s4[0], f1 = s4[1], f2 = s4[2], f3 = s4[3];
    u32x4 c_lo, c_hi;
    c_lo.x = pack2bf(f0.x, f0.y); c_lo.y = pack2bf(f0.z, f0.w);
    c_lo.z = pack2bf(f1.x, f1.y); c_lo.w = pack2bf(f1.z, f1.w);
    c_hi.x = pack2bf(f2.x, f2.y); c_hi.y = pack2bf(f2.z, f2.w);
    c_hi.z = pack2bf(f3.x, f3.y); c_hi.w = pack2bf(f3.z, f3.w);
    char* tb = ws + K16_OFF + ((size_t)head*64 + t)*8192;
    int sw = (r & 7) << 4;
    *(u32x4*)(tb + r*128 + ((c0*2)      ^ sw)) = c_lo;
    *(u32x4*)(tb + r*128 + ((c0*2 + 16) ^ sw)) = c_hi;
  } else {                               // V: transpose via LDS, then swizzled tiles [d][k]
    int tile = bx - 3072;
    int head = tile >> 6, t = tile & 63;
    int k = tid >> 2, c0 = (tid & 3)*16;
    const float4* s4 = (const float4*)(V + (size_t)head*HE + ((size_t)(t*64 + k))*64 + c0);
    float4 f0 = s4[0], f1 = s4[1], f2 = s4[2], f3 = s4[3];
    float tmp[16] = {f0.x,f0.y,f0.z,f0.w, f1.x,f1.y,f1.z,f1.w,
                     f2.x,f2.y,f2.z,f2.w, f3.x,f3.y,f3.z,f3.w};
    #pragma unroll
    for (int j = 0; j < 16; ++j) vt[k*65 + c0 + j] = tmp[j];
    __syncthreads();
    int d = tid >> 2, k0 = (tid & 3)*16;
    float v2[16];
    #pragma unroll
    for (int j = 0; j < 16; ++j) v2[j] = vt[(k0 + j)*65 + d];
    u32x4 c_lo, c_hi;
    c_lo.x = pack2bf(v2[0],  v2[1]);  c_lo.y = pack2bf(v2[2],  v2[3]);
    c_lo.z = pack2bf(v2[4],  v2[5]);  c_lo.w = pack2bf(v2[6],  v2[7]);
    c_hi.x = pack2bf(v2[8],  v2[9]);  c_hi.y = pack2bf(v2[10], v2[11]);
    c_hi.z = pack2bf(v2[12], v2[13]); c_hi.w = pack2bf(v2[14], v2[15]);
    char* tb = ws + V16_OFF + ((size_t)head*64 + t)*8192;
    int sw = (d & 7) << 4;
    *(u32x4*)(tb + d*128 + ((k0*2)      ^ sw)) = c_lo;
    *(u32x4*)(tb + d*128 + ((k0*2 + 16) ^ sw)) = c_hi;
  }
}

__global__ __launch_bounds__(256, 2) void attn_kernel(const char* __restrict__ ws,
                                                      float* __restrict__ out) {
  __shared__ __align__(16) char lds[8*8192];   // [group][dbuf][K|V] x 8KB
  int bx = blockIdx.x;
  int head = bx >> 5, qblk = bx & 31;
  int tid = threadIdx.x;
  int lane = tid & 63, w = tid >> 6;
  int l31 = lane & 31, h = lane >> 5;
  int g  = w >> 1;    // k-group: tiles [g*32, g*32+32)
  int mq = w & 1;     // q-half of the 128-row block

  const char* q16 = ws + Q16_OFF + (size_t)head*HB;
  const char* k16 = ws + K16_OFF + (size_t)head*HB;
  const char* v16 = ws + V16_OFF + (size_t)head*HB;
  int qrow0 = qblk*128 + mq*64;

  // Q fragments (B-operand of swapped QK^T): Q[qrow0+m*32+l31][t*16+h*8+e]
  bf16x8 qf[2][4];
  #pragma unroll
  for (int m = 0; m < 2; ++m)
    #pragma unroll
    for (int t = 0; t < 4; ++t)
      qf[m][t] = *(const bf16x8*)(q16 + ((size_t)(qrow0 + m*32 + l31)*64 + t*16 + h*8)*2);

  // hoisted zero C-operand: first MFMA of each S-tile reads this instead of
  // re-zeroing 64 VGPRs per tile
  f32x16 kZero;
  #pragma unroll
  for (int i = 0; i < 16; ++i) kZero[i] = 0.f;

  f32x16 o[2][2];
  #pragma unroll
  for (int m = 0; m < 2; ++m)
    #pragma unroll
    for (int nd = 0; nd < 2; ++nd)
      #pragma unroll
      for (int i = 0; i < 16; ++i) o[m][nd][i] = 0.f;

  char* ldsg = lds + g*4*8192;

  auto stage = [&](int cur, int kt) {
    const char* ktile = k16 + (size_t)(g*32 + kt)*8192;
    const char* vtile = v16 + (size_t)(g*32 + kt)*8192;
    char* lk = ldsg + (cur*2 + 0)*8192;
    char* lv = ldsg + (cur*2 + 1)*8192;
    #pragma unroll
    for (int c = 0; c < 4; ++c) {
      int off = (mq*4 + c)*1024;
      __builtin_amdgcn_global_load_lds(
          (const __attribute__((address_space(1))) void*)(ktile + off + lane*16),
          (__attribute__((address_space(3))) void*)(lk + off), 16, 0, 0);
      __builtin_amdgcn_global_load_lds(
          (const __attribute__((address_space(1))) void*)(vtile + off + lane*16),
          (__attribute__((address_space(3))) void*)(lv + off), 16, 0, 0);
    }
  };

  auto compute = [&](int cur) {
    const char* lk = ldsg + (cur*2 + 0)*8192;
    const char* lv = ldsg + (cur*2 + 1)*8192;
    // swapped QK^T: st[m][n] = S^T tile (rows k = n*32.., cols q = m*32..)
    f32x16 st[2][2];
    #pragma unroll
    for (int n = 0; n < 2; ++n) {
      bf16x8 kf[4];
      int row = n*32 + l31;
      int sw = (row & 7) << 4;
      #pragma unroll
      for (int t = 0; t < 4; ++t)
        kf[t] = *(const bf16x8*)(lk + row*128 + ((t*32 + h*16) ^ sw));
      __builtin_amdgcn_s_setprio(1);
      #pragma unroll
      for (int m = 0; m < 2; ++m) {
        f32x16 acc = __builtin_amdgcn_mfma_f32_32x32x16_bf16(kf[0], qf[m][0], kZero, 0, 0, 0);
        #pragma unroll
        for (int t = 1; t < 4; ++t)
          acc = __builtin_amdgcn_mfma_f32_32x32x16_bf16(kf[t], qf[m][t], acc, 0, 0, 0);
        st[m][n] = acc;
      }
      __builtin_amdgcn_s_setprio(0);
    }
    // pack (cvt_pk) -> half-exchange (permlane32_swap) -> packed relu (v_pk_max_f16)
    bf16x8 pa[2][4];
    #pragma unroll
    for (int m = 0; m < 2; ++m)
      #pragma unroll
      for (int n = 0; n < 2; ++n)
        #pragma unroll
        for (int kn = 0; kn < 2; ++kn) {
          uint32_t a0 = pack2bf(st[m][n][kn*8+0], st[m][n][kn*8+1]);
          uint32_t b0 = pack2bf(st[m][n][kn*8+2], st[m][n][kn*8+3]);
          uint32_t a2 = pack2bf(st[m][n][kn*8+4], st[m][n][kn*8+5]);
          uint32_t b2 = pack2bf(st[m][n][kn*8+6], st[m][n][kn*8+7]);
          // D-low stays, D-high <- S-low, S-low <- D-high, S-high stays:
          // a0' = word0 (own-lo | partner-hi), a2' = word2 (partner-lo | own-hi)
          asm("v_permlane32_swap_b32 %0, %1" : "+v"(a0), "+v"(a2));
          asm("v_permlane32_swap_b32 %0, %1" : "+v"(b0), "+v"(b2));
          union { uint32_t u[4]; bf16x8 v; } pk;
          pk.u[0] = relu2(a0);
          pk.u[1] = relu2(b0);
          pk.u[2] = relu2(a2);
          pk.u[3] = relu2(b2);
          pa[m][n*2 + kn] = pk.v;
        }
    // V fragments (B-operand): V[ks*16+h*8+e][nd*32+l31] from transposed tile
    bf16x8 vf[2][4];
    #pragma unroll
    for (int nd = 0; nd < 2; ++nd) {
      int row = nd*32 + l31;
      int sw = (row & 7) << 4;
      #pragma unroll
      for (int ks = 0; ks < 4; ++ks)
        vf[nd][ks] = *(const bf16x8*)(lv + row*128 + ((ks*32 + h*16) ^ sw));
    }
    __builtin_amdgcn_s_setprio(1);
    #pragma unroll
    for (int m = 0; m < 2; ++m)
      #pragma unroll
      for (int nd = 0; nd < 2; ++nd)
        #pragma unroll
        for (int ks = 0; ks < 4; ++ks)
          o[m][nd] = __builtin_amdgcn_mfma_f32_32x32x16_bf16(pa[m][ks], vf[nd][ks], o[m][nd], 0, 0, 0);
    __builtin_amdgcn_s_setprio(0);
  };

  stage(0, 0);
  __syncthreads();
  #pragma unroll 1
  for (int kt = 0; kt < 32; ++kt) {
    int cur = kt & 1;
    if (kt + 1 < 32) stage(cur ^ 1, kt + 1);
    compute(cur);
    __syncthreads();
  }

  // cross-k-group O reduction: g1 -> LDS, g0 adds and stores
  float* red = (float*)lds;
  if (g == 1) {
    #pragma unroll
    for (int m = 0; m < 2; ++m)
      #pragma unroll
      for (int nd = 0; nd < 2; ++nd)
        #pragma unroll
        for (int r = 0; r < 16; ++r) {
          int ql = m*32 + (r & 3) + 8*(r >> 2) + 4*h;
          red[mq*4096 + ql*64 + nd*32 + l31] = o[m][nd][r];
        }
  }
  __syncthreads();
  if (g == 0) {
    float* outh = out + (size_t)head*HE;
    #pragma unroll
    for (int m = 0; m < 2; ++m)
      #pragma unroll
      for (int nd = 0; nd < 2; ++nd)
        #pragma unroll
        for (int r = 0; r < 16; ++r) {
          int ql = m*32 + (r & 3) + 8*(r >> 2) + 4*h;
          float v = o[m][nd][r] + red[mq*4096 + ql*64 + nd*32 + l31];
          outh[(size_t)(qrow0 + ql)*64 + nd*32 + l31] = v;
        }
  }
}

extern "C" void kernel_launch(void* const* d_in, const int* in_sizes, int n_in,
                              void* d_out, int out_size, void* d_ws, size_t ws_size,
                              hipStream_t stream) {
  if (n_in < 3 || ws_size < (size_t)WS_NEED) return;  // ws too small -> fail visibly
  const float* Q = (const float*)d_in[0];
  const float* K = (const float*)d_in[1];
  const float* V = (const float*)d_in[2];
  float* out = (float*)d_out;
  char* ws = (char*)d_ws;
  hipLaunchKernelGGL(prepass_kernel, dim3(4096), dim3(256), 0, stream, Q, K, V, ws);
  hipLaunchKernelGGL(attn_kernel,    dim3(512),  dim3(256), 0, stream, ws, out);
}

// Round 4
// 86.159 us; speedup vs baseline: 1.1268x; 1.0192x over previous
//
#include <hip/hip_runtime.h>
#include <hip/hip_bf16.h>
#include <stdint.h>

// DotReluAttention: out = relu(Q K^T / 64) V   (B=2,H=8,S=4096,D=64, fp32 io)
// Pre-pass: fp32->bf16 into ws (Q/64 row-major; K 64x64 swizzled tiles; V transposed+swizzled tiles).
// Main: 32x32x16 bf16 MFMA, swapped QK^T, in-register P via permlane32_swap,
//       packed-f16 relu (inline asm), hoisted zero acc, setprio, 2-way K-split,
//       T3/T4 counted-vmcnt double-buffer pipeline (raw s_barrier, never vmcnt(0) in loop).

#define NH 16
#define SEQ 4096
#define DD 64
#define HE (SEQ*DD)            // 262144 elems / head
#define HB (HE*2)              // 524288 bytes / head (bf16)
#define Q16_OFF 0
#define K16_OFF (NH*HB)        // 8388608
#define V16_OFF (2*NH*HB)      // 16777216
#define WS_NEED (3*NH*HB)      // 25165824

typedef __attribute__((ext_vector_type(8)))  short    bf16x8;
typedef __attribute__((ext_vector_type(16))) float    f32x16;
typedef __attribute__((ext_vector_type(4)))  uint32_t u32x4;

__device__ inline uint32_t f2bf1(float f) {
  return (uint32_t)__builtin_bit_cast(unsigned short, __float2bfloat16(f));
}
__device__ inline uint32_t pack2bf(float a, float b) {
  return f2bf1(a) | (f2bf1(b) << 16);
}
// relu on a packed pair of bf16 via v_pk_max_f16: bit-pattern order-isomorphism
// for finite positives + sign in bit15 => max(x, +0) zeroes exactly the
// negative halves. |S| here is far from any f16-special pattern window.
__device__ inline uint32_t relu2(uint32_t w) {
  uint32_t r;
  asm("v_pk_max_f16 %0, %1, 0" : "=v"(r) : "v"(w));
  return r;
}

__global__ __launch_bounds__(256) void prepass_kernel(const float* __restrict__ Q,
                                                      const float* __restrict__ K,
                                                      const float* __restrict__ V,
                                                      char* __restrict__ ws) {
  __shared__ float vt[64*65];
  int bx = blockIdx.x, tid = threadIdx.x;
  if (bx < 2048) {                       // Q: convert + scale 1/64, row-major
    size_t base = ((size_t)bx*256 + tid)*8;
    const float4* s = (const float4*)(Q + base);
    float4 a = s[0], b = s[1];
    const float sc = 1.0f/64.0f;
    u32x4 o;
    o.x = pack2bf(a.x*sc, a.y*sc);
    o.y = pack2bf(a.z*sc, a.w*sc);
    o.z = pack2bf(b.x*sc, b.y*sc);
    o.w = pack2bf(b.z*sc, b.w*sc);
    *(u32x4*)(ws + Q16_OFF + base*2) = o;
  } else if (bx < 3072) {                // K: 64x64 tiles, row-major, XOR-swizzled
    int tile = bx - 2048;
    int head = tile >> 6, t = tile & 63;
    int r = tid >> 2, c0 = (tid & 3) * 16;
    const float4* s4 = (const float4*)(K + (size_t)head*HE + ((size_t)(t*64 + r))*64 + c0);
    float4 f0 = s4[0], f1 = s4[1], f2 = s4[2], f3 = s4[3];
    u32x4 c_lo, c_hi;
    c_lo.x = pack2bf(f0.x, f0.y); c_lo.y = pack2bf(f0.z, f0.w);
    c_lo.z = pack2bf(f1.x, f1.y); c_lo.w = pack2bf(f1.z, f1.w);
    c_hi.x = pack2bf(f2.x, f2.y); c_hi.y = pack2bf(f2.z, f2.w);
    c_hi.z = pack2bf(f3.x, f3.y); c_hi.w = pack2bf(f3.z, f3.w);
    char* tb = ws + K16_OFF + ((size_t)head*64 + t)*8192;
    int sw = (r & 7) << 4;
    *(u32x4*)(tb + r*128 + ((c0*2)      ^ sw)) = c_lo;
    *(u32x4*)(tb + r*128 + ((c0*2 + 16) ^ sw)) = c_hi;
  } else {                               // V: transpose via LDS, then swizzled tiles [d][k]
    int tile = bx - 3072;
    int head = tile >> 6, t = tile & 63;
    int k = tid >> 2, c0 = (tid & 3)*16;
    const float4* s4 = (const float4*)(V + (size_t)head*HE + ((size_t)(t*64 + k))*64 + c0);
    float4 f0 = s4[0], f1 = s4[1], f2 = s4[2], f3 = s4[3];
    float tmp[16] = {f0.x,f0.y,f0.z,f0.w, f1.x,f1.y,f1.z,f1.w,
                     f2.x,f2.y,f2.z,f2.w, f3.x,f3.y,f3.z,f3.w};
    #pragma unroll
    for (int j = 0; j < 16; ++j) vt[k*65 + c0 + j] = tmp[j];
    __syncthreads();
    int d = tid >> 2, k0 = (tid & 3)*16;
    float v2[16];
    #pragma unroll
    for (int j = 0; j < 16; ++j) v2[j] = vt[(k0 + j)*65 + d];
    u32x4 c_lo, c_hi;
    c_lo.x = pack2bf(v2[0],  v2[1]);  c_lo.y = pack2bf(v2[2],  v2[3]);
    c_lo.z = pack2bf(v2[4],  v2[5]);  c_lo.w = pack2bf(v2[6],  v2[7]);
    c_hi.x = pack2bf(v2[8],  v2[9]);  c_hi.y = pack2bf(v2[10], v2[11]);
    c_hi.z = pack2bf(v2[12], v2[13]); c_hi.w = pack2bf(v2[14], v2[15]);
    char* tb = ws + V16_OFF + ((size_t)head*64 + t)*8192;
    int sw = (d & 7) << 4;
    *(u32x4*)(tb + d*128 + ((k0*2)      ^ sw)) = c_lo;
    *(u32x4*)(tb + d*128 + ((k0*2 + 16) ^ sw)) = c_hi;
  }
}

__global__ __launch_bounds__(256, 2) void attn_kernel(const char* __restrict__ ws,
                                                      float* __restrict__ out) {
  __shared__ __align__(16) char lds[8*8192];   // [group][dbuf][K|V] x 8KB
  int bx = blockIdx.x;
  int head = bx >> 5, qblk = bx & 31;
  int tid = threadIdx.x;
  int lane = tid & 63, w = tid >> 6;
  int l31 = lane & 31, h = lane >> 5;
  int g  = w >> 1;    // k-group: tiles [g*32, g*32+32)
  int mq = w & 1;     // q-half of the 128-row block

  const char* q16 = ws + Q16_OFF + (size_t)head*HB;
  const char* k16 = ws + K16_OFF + (size_t)head*HB;
  const char* v16 = ws + V16_OFF + (size_t)head*HB;
  int qrow0 = qblk*128 + mq*64;

  // Q fragments (B-operand of swapped QK^T): Q[qrow0+m*32+l31][t*16+h*8+e]
  bf16x8 qf[2][4];
  #pragma unroll
  for (int m = 0; m < 2; ++m)
    #pragma unroll
    for (int t = 0; t < 4; ++t)
      qf[m][t] = *(const bf16x8*)(q16 + ((size_t)(qrow0 + m*32 + l31)*64 + t*16 + h*8)*2);

  // hoisted zero C-operand
  f32x16 kZero;
  #pragma unroll
  for (int i = 0; i < 16; ++i) kZero[i] = 0.f;

  f32x16 o[2][2];
  #pragma unroll
  for (int m = 0; m < 2; ++m)
    #pragma unroll
    for (int nd = 0; nd < 2; ++nd)
      #pragma unroll
      for (int i = 0; i < 16; ++i) o[m][nd][i] = 0.f;

  char* ldsg = lds + g*4*8192;

  // 8 global_load_lds per wave per tile (4 K-quarters + 4 V-quarters)
  auto stage = [&](int cur, int kt) {
    const char* ktile = k16 + (size_t)(g*32 + kt)*8192;
    const char* vtile = v16 + (size_t)(g*32 + kt)*8192;
    char* lk = ldsg + (cur*2 + 0)*8192;
    char* lv = ldsg + (cur*2 + 1)*8192;
    #pragma unroll
    for (int c = 0; c < 4; ++c) {
      int off = (mq*4 + c)*1024;
      __builtin_amdgcn_global_load_lds(
          (const __attribute__((address_space(1))) void*)(ktile + off + lane*16),
          (__attribute__((address_space(3))) void*)(lk + off), 16, 0, 0);
      __builtin_amdgcn_global_load_lds(
          (const __attribute__((address_space(1))) void*)(vtile + off + lane*16),
          (__attribute__((address_space(3))) void*)(lv + off), 16, 0, 0);
    }
  };

  auto compute = [&](int cur) {
    const char* lk = ldsg + (cur*2 + 0)*8192;
    const char* lv = ldsg + (cur*2 + 1)*8192;
    // swapped QK^T: st[m][n] = S^T tile (rows k = n*32.., cols q = m*32..)
    f32x16 st[2][2];
    #pragma unroll
    for (int n = 0; n < 2; ++n) {
      bf16x8 kf[4];
      int row = n*32 + l31;
      int sw = (row & 7) << 4;
      #pragma unroll
      for (int t = 0; t < 4; ++t)
        kf[t] = *(const bf16x8*)(lk + row*128 + ((t*32 + h*16) ^ sw));
      __builtin_amdgcn_s_setprio(1);
      #pragma unroll
      for (int m = 0; m < 2; ++m) {
        f32x16 acc = __builtin_amdgcn_mfma_f32_32x32x16_bf16(kf[0], qf[m][0], kZero, 0, 0, 0);
        #pragma unroll
        for (int t = 1; t < 4; ++t)
          acc = __builtin_amdgcn_mfma_f32_32x32x16_bf16(kf[t], qf[m][t], acc, 0, 0, 0);
        st[m][n] = acc;
      }
      __builtin_amdgcn_s_setprio(0);
    }
    // V fragments issued before pack so their LDS latency hides under the VALU pack
    bf16x8 vf[2][4];
    #pragma unroll
    for (int nd = 0; nd < 2; ++nd) {
      int row = nd*32 + l31;
      int sw = (row & 7) << 4;
      #pragma unroll
      for (int ks = 0; ks < 4; ++ks)
        vf[nd][ks] = *(const bf16x8*)(lv + row*128 + ((ks*32 + h*16) ^ sw));
    }
    // pack (cvt_pk) -> half-exchange (permlane32_swap) -> packed relu (v_pk_max_f16)
    bf16x8 pa[2][4];
    #pragma unroll
    for (int m = 0; m < 2; ++m)
      #pragma unroll
      for (int n = 0; n < 2; ++n)
        #pragma unroll
        for (int kn = 0; kn < 2; ++kn) {
          uint32_t a0 = pack2bf(st[m][n][kn*8+0], st[m][n][kn*8+1]);
          uint32_t b0 = pack2bf(st[m][n][kn*8+2], st[m][n][kn*8+3]);
          uint32_t a2 = pack2bf(st[m][n][kn*8+4], st[m][n][kn*8+5]);
          uint32_t b2 = pack2bf(st[m][n][kn*8+6], st[m][n][kn*8+7]);
          asm("v_permlane32_swap_b32 %0, %1" : "+v"(a0), "+v"(a2));
          asm("v_permlane32_swap_b32 %0, %1" : "+v"(b0), "+v"(b2));
          union { uint32_t u[4]; bf16x8 v; } pk;
          pk.u[0] = relu2(a0);
          pk.u[1] = relu2(b0);
          pk.u[2] = relu2(a2);
          pk.u[3] = relu2(b2);
          pa[m][n*2 + kn] = pk.v;
        }
    __builtin_amdgcn_s_setprio(1);
    #pragma unroll
    for (int m = 0; m < 2; ++m)
      #pragma unroll
      for (int nd = 0; nd < 2; ++nd)
        #pragma unroll
        for (int ks = 0; ks < 4; ++ks)
          o[m][nd] = __builtin_amdgcn_mfma_f32_32x32x16_bf16(pa[m][ks], vf[nd][ks], o[m][nd], 0, 0, 0);
    __builtin_amdgcn_s_setprio(0);
  };

  // T3/T4 pipeline: 2 tiles in flight, counted vmcnt, raw barriers (no full drain).
  stage(0, 0);
  stage(1, 1);
  #pragma unroll 1
  for (int kt = 0; kt < 30; ++kt) {
    int cur = kt & 1;
    asm volatile("s_waitcnt vmcnt(8)" ::: "memory");  // my 8 loads for tile kt done
    __builtin_amdgcn_s_barrier();                     // all waves' tile-kt loads done
    __builtin_amdgcn_sched_barrier(0);
    compute(cur);
    __builtin_amdgcn_sched_barrier(0);
    __builtin_amdgcn_s_barrier();                     // all waves done reading buf cur
    stage(cur, kt + 2);                               // refill freed buffer
  }
  // kt = 30: tiles 30,31 in flight (16 loads)
  asm volatile("s_waitcnt vmcnt(8)" ::: "memory");
  __builtin_amdgcn_s_barrier();
  __builtin_amdgcn_sched_barrier(0);
  compute(0);
  __builtin_amdgcn_sched_barrier(0);
  __builtin_amdgcn_s_barrier();
  // kt = 31: last tile
  asm volatile("s_waitcnt vmcnt(0)" ::: "memory");
  __builtin_amdgcn_s_barrier();
  __builtin_amdgcn_sched_barrier(0);
  compute(1);

  // cross-k-group O reduction: g1 -> LDS, g0 adds and stores
  __syncthreads();
  float* red = (float*)lds;
  if (g == 1) {
    #pragma unroll
    for (int m = 0; m < 2; ++m)
      #pragma unroll
      for (int nd = 0; nd < 2; ++nd)
        #pragma unroll
        for (int r = 0; r < 16; ++r) {
          int ql = m*32 + (r & 3) + 8*(r >> 2) + 4*h;
          red[mq*4096 + ql*64 + nd*32 + l31] = o[m][nd][r];
        }
  }
  __syncthreads();
  if (g == 0) {
    float* outh = out + (size_t)head*HE;
    #pragma unroll
    for (int m = 0; m < 2; ++m)
      #pragma unroll
      for (int nd = 0; nd < 2; ++nd)
        #pragma unroll
        for (int r = 0; r < 16; ++r) {
          int ql = m*32 + (r & 3) + 8*(r >> 2) + 4*h;
          float v = o[m][nd][r] + red[mq*4096 + ql*64 + nd*32 + l31];
          outh[(size_t)(qrow0 + ql)*64 + nd*32 + l31] = v;
        }
  }
}

extern "C" void kernel_launch(void* const* d_in, const int* in_sizes, int n_in,
                              void* d_out, int out_size, void* d_ws, size_t ws_size,
                              hipStream_t stream) {
  if (n_in < 3 || ws_size < (size_t)WS_NEED) return;  // ws too small -> fail visibly
  const float* Q = (const float*)d_in[0];
  const float* K = (const float*)d_in[1];
  const float* V = (const float*)d_in[2];
  float* out = (float*)d_out;
  char* ws = (char*)d_ws;
  hipLaunchKernelGGL(prepass_kernel, dim3(4096), dim3(256), 0, stream, Q, K, V, ws);
  hipLaunchKernelGGL(attn_kernel,    dim3(512),  dim3(256), 0, stream, ws, out);
}